// Round 1
// baseline (260.067 us; speedup 1.0000x reference)
//
#include <hip/hip_runtime.h>

typedef short bf16x8 __attribute__((ext_vector_type(8)));
typedef float f32x4 __attribute__((ext_vector_type(4)));
typedef unsigned short u16;

#define NB 8
#define NS 1024
#define NE 768
#define NH 12
#define ND 64

__device__ __forceinline__ u16 f2bf(float f){
  unsigned u = __float_as_uint(f);
  u += 0x7fffu + ((u >> 16) & 1u);
  return (u16)(u >> 16);
}

typedef const __attribute__((address_space(1))) unsigned int glb_u32;
typedef __attribute__((address_space(3))) unsigned int lds_u32;

__device__ __forceinline__ void async16(const void* g, void* l){
  __builtin_amdgcn_global_load_lds((glb_u32*)g, (lds_u32*)l, 16, 0, 0);
}

// ---------------- fp32 -> bf16 convert ----------------
__global__ void cvt_kernel(const float* __restrict__ src, u16* __restrict__ dst, int n4){
  int i = blockIdx.x * 256 + threadIdx.x;
  if (i < n4){
    float4 v = ((const float4*)src)[i];
    ushort4 o;
    o.x = f2bf(v.x); o.y = f2bf(v.y); o.z = f2bf(v.z); o.w = f2bf(v.w);
    ((ushort4*)dst)[i] = o;
  }
}

// ---------------- lengths from prefix mask (dtype auto-detect) ----------------
__global__ void lengths_kernel(const unsigned int* __restrict__ mi, int* __restrict__ lens){
  __shared__ int isByte;
  int tid = threadIdx.x;
  int any = 0;
  // first 2048 words are in-bounds under both interpretations (8 KB)
  for (int i = tid; i < 2048; i += 512) any |= (mi[i] > 1u) ? 1 : 0;
  if (tid == 0) isByte = 0;
  __syncthreads();
  if (any) atomicOr(&isByte, 1);
  __syncthreads();
  int byteMode = isByte;
  int b = tid >> 6, lane = tid & 63;
  int cnt = 0;
  if (byteMode){
    const unsigned char* p = (const unsigned char*)mi;
    for (int j = 0; j < 16; ++j) cnt += p[b*NS + j*64 + lane] ? 1 : 0;
  } else {
    for (int j = 0; j < 16; ++j) cnt += mi[b*NS + j*64 + lane] ? 1 : 0;
  }
  for (int o = 1; o < 64; o <<= 1) cnt += __shfl_xor(cnt, o, 64);
  if (lane == 0) lens[b] = cnt;
}

// ---------------- QKV projection GEMM: [8192,768] x [2304,768]^T ----------------
// epilogue scatters to q(b,h,s,d), k(b,h,s,d), v(b,h,d,s) in bf16
__global__ __launch_bounds__(256, 2) void gemm_qkv(
    const u16* __restrict__ A, const u16* __restrict__ Bw,
    const float* __restrict__ bias,
    u16* __restrict__ qb, u16* __restrict__ kb, u16* __restrict__ vb)
{
  __shared__ __align__(16) u16 smA[128*32];
  __shared__ __align__(16) u16 smB[128*32];
  const int tid = threadIdx.x;
  const int lane = tid & 63;
  const int wave = tid >> 6;
  const int wm = wave >> 1, wn = wave & 1;
  const int m0 = blockIdx.y * 128;
  const int n0 = blockIdx.x * 128;
  const int K = NE;

  f32x4 acc[4][4] = {};

  for (int kt = 0; kt < K; kt += 32){
    #pragma unroll
    for (int j = 0; j < 2; ++j){
      int c = j*256 + tid;
      int row = c >> 2;
      int off = (c & 3) * 16;
      const char* gA = (const char*)A + ((size_t)(m0+row)*K + kt)*2 + off;
      const char* gB = (const char*)Bw + ((size_t)(n0+row)*K + kt)*2 + off;
      char* lA = (char*)smA + (size_t)(j*256 + wave*64)*16;
      char* lB = (char*)smB + (size_t)(j*256 + wave*64)*16;
      async16(gA, lA);
      async16(gB, lB);
    }
    __syncthreads();
    int rA = wm*64 + (lane & 15);
    int rB = wn*64 + (lane & 15);
    int kk = (lane >> 4) * 8;
    bf16x8 av[4], bv[4];
    #pragma unroll
    for (int i = 0; i < 4; ++i){
      av[i] = *(const bf16x8*)&smA[(rA + i*16)*32 + kk];
      bv[i] = *(const bf16x8*)&smB[(rB + i*16)*32 + kk];
    }
    #pragma unroll
    for (int mi = 0; mi < 4; ++mi)
      #pragma unroll
      for (int ni = 0; ni < 4; ++ni)
        acc[mi][ni] = __builtin_amdgcn_mfma_f32_16x16x32_bf16(av[mi], bv[ni], acc[mi][ni], 0, 0, 0);
    __syncthreads();
  }

  // epilogue: n = which*768 + h*64 + d
  int colbase = n0 + wn*64 + (lane & 15);
  #pragma unroll
  for (int ni = 0; ni < 4; ++ni){
    int gcol = colbase + ni*16;
    int which = gcol / NE;
    int rem = gcol - which*NE;
    int hh = rem >> 6;
    int dd = rem & 63;
    float bval = bias[gcol];
    #pragma unroll
    for (int mi = 0; mi < 4; ++mi){
      int rowb = m0 + wm*64 + mi*16 + (lane >> 4)*4;
      #pragma unroll
      for (int r = 0; r < 4; ++r){
        int grow = rowb + r;
        int bb = grow >> 10;
        int ss = grow & 1023;
        u16 bf = f2bf(acc[mi][ni][r] + bval);
        int bh = bb*NH + hh;
        if (which == 0)      qb[((size_t)bh*NS + ss)*ND + dd] = bf;
        else if (which == 1) kb[((size_t)bh*NS + ss)*ND + dd] = bf;
        else                 vb[((size_t)bh*ND + dd)*NS + ss] = bf;
      }
    }
  }
}

// ---------------- flash attention ----------------
__global__ __launch_bounds__(256, 2) void attn_kernel(
    const u16* __restrict__ qb, const u16* __restrict__ kb,
    const u16* __restrict__ vb, const int* __restrict__ lens,
    u16* __restrict__ ctx)
{
  __shared__ __align__(16) u16 smQ[2][64*32];
  __shared__ __align__(16) u16 smK[2][64*32];
  __shared__ __align__(16) u16 smV[2][64*32];
  __shared__ __align__(16) u16 smP[4][16*72];

  const int tid = threadIdx.x, lane = tid & 63, wave = tid >> 6;
  const int bh = blockIdx.y;
  const int b = bh / NH;
  const int h = bh - b*NH;
  const int q0 = blockIdx.x * 64;
  const int len = lens[b];
  const float scale = 0.125f;

  // stage Q tile (64 rows x 64 d), two 32-d chunks
  {
    int c = tid; int r = c >> 2; int off = (c & 3)*16;
    #pragma unroll
    for (int qc = 0; qc < 2; ++qc){
      const char* g = (const char*)qb + (size_t)(bh*NS + q0 + r)*128 + qc*64 + off;
      async16(g, (char*)smQ[qc] + wave*1024);
    }
  }

  float m_i[4], l_i[4];
  f32x4 accO[4] = {};
  #pragma unroll
  for (int r = 0; r < 4; ++r){ m_i[r] = -1e30f; l_i[r] = 0.f; }

  const int ntiles = (len + 63) >> 6;
  const int kk = (lane >> 4) * 8;

  for (int t = 0; t < ntiles; ++t){
    int key0 = t*64;
    __syncthreads();   // protect smK/smV from previous iteration's readers
    {
      int c = tid; int r = c >> 2; int off = (c & 3)*16;
      #pragma unroll
      for (int kc = 0; kc < 2; ++kc){
        const char* gk = (const char*)kb + (size_t)(bh*NS + key0 + r)*128 + kc*64 + off;
        async16(gk, (char*)smK[kc] + wave*1024);
        const char* gv = (const char*)vb + ((size_t)(bh*ND + r)*NS + key0 + kc*32)*2 + off;
        async16(gv, (char*)smV[kc] + wave*1024);
      }
    }
    __syncthreads();

    // S = Q K^T (this wave: 16 q-rows x 64 keys)
    f32x4 accS[4] = {};
    int mrow = wave*16 + (lane & 15);
    #pragma unroll
    for (int kc = 0; kc < 2; ++kc){
      bf16x8 aq = *(const bf16x8*)&smQ[kc][mrow*32 + kk];
      #pragma unroll
      for (int ni = 0; ni < 4; ++ni){
        bf16x8 bk = *(const bf16x8*)&smK[kc][(ni*16 + (lane & 15))*32 + kk];
        accS[ni] = __builtin_amdgcn_mfma_f32_16x16x32_bf16(aq, bk, accS[ni], 0, 0, 0);
      }
    }

    // online softmax (row = (lane>>4)*4 + r, col = ni*16 + (lane&15))
    #pragma unroll
    for (int r = 0; r < 4; ++r){
      float sv[4];
      float mx = -1e30f;
      #pragma unroll
      for (int ni = 0; ni < 4; ++ni){
        int key = key0 + ni*16 + (lane & 15);
        float x = accS[ni][r] * scale;
        x = (key < len) ? x : -1e30f;
        sv[ni] = x;
        mx = fmaxf(mx, x);
      }
      #pragma unroll
      for (int o = 1; o < 16; o <<= 1) mx = fmaxf(mx, __shfl_xor(mx, o, 64));
      float mnew = fmaxf(m_i[r], mx);
      float alpha = __expf(m_i[r] - mnew);
      float sum = 0.f;
      int prow = (lane >> 4)*4 + r;
      #pragma unroll
      for (int ni = 0; ni < 4; ++ni){
        float p = __expf(sv[ni] - mnew);
        sum += p;
        smP[wave][prow*72 + ni*16 + (lane & 15)] = f2bf(p);
      }
      #pragma unroll
      for (int o = 1; o < 16; o <<= 1) sum += __shfl_xor(sum, o, 64);
      l_i[r] = l_i[r]*alpha + sum;
      m_i[r] = mnew;
      #pragma unroll
      for (int di = 0; di < 4; ++di) accO[di][r] *= alpha;
    }
    asm volatile("s_waitcnt lgkmcnt(0)" ::: "memory");

    // O += P V   (P: A-layout from LDS; V^T chunks: contiguous keys)
    #pragma unroll
    for (int kc = 0; kc < 2; ++kc){
      bf16x8 ap = *(const bf16x8*)&smP[wave][(lane & 15)*72 + kc*32 + kk];
      #pragma unroll
      for (int di = 0; di < 4; ++di){
        bf16x8 bv2 = *(const bf16x8*)&smV[kc][(di*16 + (lane & 15))*32 + kk];
        accO[di] = __builtin_amdgcn_mfma_f32_16x16x32_bf16(ap, bv2, accO[di], 0, 0, 0);
      }
    }
  }

  // epilogue: ctx(b,s,e) bf16; query rows >= len -> 0
  #pragma unroll
  for (int r = 0; r < 4; ++r){
    int srow = q0 + wave*16 + (lane >> 4)*4 + r;
    float inv = (l_i[r] > 0.f) ? 1.0f / l_i[r] : 0.f;
    bool valid = srow < len;
    #pragma unroll
    for (int di = 0; di < 4; ++di){
      float v = valid ? accO[di][r] * inv : 0.f;
      ctx[(size_t)(b*NS + srow)*NE + h*ND + di*16 + (lane & 15)] = f2bf(v);
    }
  }
}

// ---------------- output projection GEMM: [8192,768] x [768,768]^T -> fp32 ----------------
__global__ __launch_bounds__(256, 2) void gemm_out(
    const u16* __restrict__ A, const u16* __restrict__ Bw,
    const float* __restrict__ bias, float* __restrict__ out)
{
  __shared__ __align__(16) u16 smA[128*32];
  __shared__ __align__(16) u16 smB[128*32];
  const int tid = threadIdx.x;
  const int lane = tid & 63;
  const int wave = tid >> 6;
  const int wm = wave >> 1, wn = wave & 1;
  const int m0 = blockIdx.y * 128;
  const int n0 = blockIdx.x * 128;
  const int K = NE;

  f32x4 acc[4][4] = {};

  for (int kt = 0; kt < K; kt += 32){
    #pragma unroll
    for (int j = 0; j < 2; ++j){
      int c = j*256 + tid;
      int row = c >> 2;
      int off = (c & 3) * 16;
      const char* gA = (const char*)A + ((size_t)(m0+row)*K + kt)*2 + off;
      const char* gB = (const char*)Bw + ((size_t)(n0+row)*K + kt)*2 + off;
      char* lA = (char*)smA + (size_t)(j*256 + wave*64)*16;
      char* lB = (char*)smB + (size_t)(j*256 + wave*64)*16;
      async16(gA, lA);
      async16(gB, lB);
    }
    __syncthreads();
    int rA = wm*64 + (lane & 15);
    int rB = wn*64 + (lane & 15);
    int kk = (lane >> 4) * 8;
    bf16x8 av[4], bv[4];
    #pragma unroll
    for (int i = 0; i < 4; ++i){
      av[i] = *(const bf16x8*)&smA[(rA + i*16)*32 + kk];
      bv[i] = *(const bf16x8*)&smB[(rB + i*16)*32 + kk];
    }
    #pragma unroll
    for (int mi = 0; mi < 4; ++mi)
      #pragma unroll
      for (int ni = 0; ni < 4; ++ni)
        acc[mi][ni] = __builtin_amdgcn_mfma_f32_16x16x32_bf16(av[mi], bv[ni], acc[mi][ni], 0, 0, 0);
    __syncthreads();
  }

  int colbase = n0 + wn*64 + (lane & 15);
  #pragma unroll
  for (int ni = 0; ni < 4; ++ni){
    int gcol = colbase + ni*16;
    float bval = bias[gcol];
    #pragma unroll
    for (int mi = 0; mi < 4; ++mi){
      int rowb = m0 + wm*64 + mi*16 + (lane >> 4)*4;
      #pragma unroll
      for (int r = 0; r < 4; ++r){
        int grow = rowb + r;
        out[(size_t)grow*NE + gcol] = acc[mi][ni][r] + bval;
      }
    }
  }
}

extern "C" void kernel_launch(void* const* d_in, const int* in_sizes, int n_in,
                              void* d_out, int out_size, void* d_ws, size_t ws_size,
                              hipStream_t stream)
{
  const float* x    = (const float*)d_in[0];
  const void*  mask = d_in[1];
  const float* wqkv = (const float*)d_in[2];
  const float* bqkv = (const float*)d_in[3];
  const float* wout = (const float*)d_in[4];
  const float* bout = (const float*)d_in[5];

  char* ws = (char*)d_ws;
  u16* xb    = (u16*)(ws + 0);         // 8192*768*2   = 12,582,912
  u16* wqkvb = (u16*)(ws + 12582912);  // 2304*768*2   =  3,538,944
  u16* woutb = (u16*)(ws + 16121856);  // 768*768*2    =  1,179,648
  u16* qbuf  = (u16*)(ws + 17301504);  // 96*1024*64*2 = 12,582,912  (b,h,s,d)
  u16* kbuf  = (u16*)(ws + 29884416);  // same          (b,h,s,d)
  u16* vbuf  = (u16*)(ws + 42467328);  // same          (b,h,d,s)
  u16* ctxb  = (u16*)(ws + 55050240);  // 8192*768*2   = 12,582,912  (b,s,e)
  int* lens  = (int*)(ws + 67633152);  // 8 ints

  cvt_kernel<<<6144, 256, 0, stream>>>(x,    xb,    6291456/4);
  cvt_kernel<<<1728, 256, 0, stream>>>(wqkv, wqkvb, 1769472/4);
  cvt_kernel<<<576,  256, 0, stream>>>(wout, woutb, 589824/4);
  lengths_kernel<<<1, 512, 0, stream>>>((const unsigned int*)mask, lens);
  gemm_qkv<<<dim3(18, 64), 256, 0, stream>>>(xb, wqkvb, bqkv, qbuf, kbuf, vbuf);
  attn_kernel<<<dim3(16, 96), 256, 0, stream>>>(qbuf, kbuf, vbuf, lens, ctxb);
  gemm_out<<<dim3(6, 64), 256, 0, stream>>>(ctxb, woutb, bout, (float*)d_out);
}

// Round 2
// 233.392 us; speedup vs baseline: 1.1143x; 1.1143x over previous
//
#include <hip/hip_runtime.h>

typedef short bf16x8 __attribute__((ext_vector_type(8)));
typedef float f32x4 __attribute__((ext_vector_type(4)));
typedef unsigned short u16;

#define NB 8
#define NS 1024
#define NE 768
#define NH 12
#define ND 64
#define QSCALE 0.18033688011112042f   // 0.125 * log2(e): scores land in log2 domain

__device__ __forceinline__ u16 f2bf(float f){
  unsigned u = __float_as_uint(f);
  u += 0x7fffu + ((u >> 16) & 1u);
  return (u16)(u >> 16);
}

// pack two fp32 -> two bf16 (round-half-up) in one u32 via v_perm
__device__ __forceinline__ unsigned pack2bf(float a, float b){
  unsigned ua = __float_as_uint(a) + 0x8000u;
  unsigned ub = __float_as_uint(b) + 0x8000u;
  return __builtin_amdgcn_perm(ub, ua, 0x07060302u);
}

#define EXP2(x) __builtin_amdgcn_exp2f(x)

typedef const __attribute__((address_space(1))) unsigned int glb_u32;
typedef __attribute__((address_space(3))) unsigned int lds_u32;

__device__ __forceinline__ void async16(const void* g, void* l){
  __builtin_amdgcn_global_load_lds((glb_u32*)g, (lds_u32*)l, 16, 0, 0);
}

// ---------------- fp32 -> bf16 convert ----------------
__global__ void cvt_kernel(const float* __restrict__ src, u16* __restrict__ dst, int n4){
  int i = blockIdx.x * 256 + threadIdx.x;
  if (i < n4){
    float4 v = ((const float4*)src)[i];
    ushort4 o;
    o.x = f2bf(v.x); o.y = f2bf(v.y); o.z = f2bf(v.z); o.w = f2bf(v.w);
    ((ushort4*)dst)[i] = o;
  }
}

// ---------------- lengths from prefix mask (dtype auto-detect) ----------------
__global__ void lengths_kernel(const unsigned int* __restrict__ mi, int* __restrict__ lens){
  __shared__ int isByte;
  int tid = threadIdx.x;
  int any = 0;
  for (int i = tid; i < 2048; i += 512) any |= (mi[i] > 1u) ? 1 : 0;
  if (tid == 0) isByte = 0;
  __syncthreads();
  if (any) atomicOr(&isByte, 1);
  __syncthreads();
  int byteMode = isByte;
  int b = tid >> 6, lane = tid & 63;
  int cnt = 0;
  if (byteMode){
    const unsigned char* p = (const unsigned char*)mi;
    for (int j = 0; j < 16; ++j) cnt += p[b*NS + j*64 + lane] ? 1 : 0;
  } else {
    for (int j = 0; j < 16; ++j) cnt += mi[b*NS + j*64 + lane] ? 1 : 0;
  }
  for (int o = 1; o < 64; o <<= 1) cnt += __shfl_xor(cnt, o, 64);
  if (lane == 0) lens[b] = cnt;
}

// ---------------- QKV projection GEMM: [8192,768] x [2304,768]^T ----------------
// epilogue scatters to q(b,h,s,d) [pre-scaled by 0.125*log2e], k(b,h,s,d), v(b,h,d,s)
__global__ __launch_bounds__(256, 2) void gemm_qkv(
    const u16* __restrict__ A, const u16* __restrict__ Bw,
    const float* __restrict__ bias,
    u16* __restrict__ qb, u16* __restrict__ kb, u16* __restrict__ vb)
{
  __shared__ __align__(16) u16 smA[128*32];
  __shared__ __align__(16) u16 smB[128*32];
  const int tid = threadIdx.x;
  const int lane = tid & 63;
  const int wave = tid >> 6;
  const int wm = wave >> 1, wn = wave & 1;
  const int m0 = blockIdx.y * 128;
  const int n0 = blockIdx.x * 128;
  const int K = NE;

  f32x4 acc[4][4] = {};

  for (int kt = 0; kt < K; kt += 32){
    #pragma unroll
    for (int j = 0; j < 2; ++j){
      int c = j*256 + tid;
      int row = c >> 2;
      int off = (c & 3) * 16;
      const char* gA = (const char*)A + ((size_t)(m0+row)*K + kt)*2 + off;
      const char* gB = (const char*)Bw + ((size_t)(n0+row)*K + kt)*2 + off;
      char* lA = (char*)smA + (size_t)(j*256 + wave*64)*16;
      char* lB = (char*)smB + (size_t)(j*256 + wave*64)*16;
      async16(gA, lA);
      async16(gB, lB);
    }
    __syncthreads();
    int rA = wm*64 + (lane & 15);
    int rB = wn*64 + (lane & 15);
    int kk = (lane >> 4) * 8;
    bf16x8 av[4], bv[4];
    #pragma unroll
    for (int i = 0; i < 4; ++i){
      av[i] = *(const bf16x8*)&smA[(rA + i*16)*32 + kk];
      bv[i] = *(const bf16x8*)&smB[(rB + i*16)*32 + kk];
    }
    #pragma unroll
    for (int mi = 0; mi < 4; ++mi)
      #pragma unroll
      for (int ni = 0; ni < 4; ++ni)
        acc[mi][ni] = __builtin_amdgcn_mfma_f32_16x16x32_bf16(av[mi], bv[ni], acc[mi][ni], 0, 0, 0);
    __syncthreads();
  }

  // epilogue: n = which*768 + h*64 + d
  int colbase = n0 + wn*64 + (lane & 15);
  #pragma unroll
  for (int ni = 0; ni < 4; ++ni){
    int gcol = colbase + ni*16;
    int which = gcol / NE;
    int rem = gcol - which*NE;
    int hh = rem >> 6;
    int dd = rem & 63;
    float bval = bias[gcol];
    float sc = (which == 0) ? QSCALE : 1.0f;
    #pragma unroll
    for (int mi = 0; mi < 4; ++mi){
      int rowb = m0 + wm*64 + mi*16 + (lane >> 4)*4;
      #pragma unroll
      for (int r = 0; r < 4; ++r){
        int grow = rowb + r;
        int bb = grow >> 10;
        int ss = grow & 1023;
        u16 bf = f2bf((acc[mi][ni][r] + bval) * sc);
        int bh = bb*NH + hh;
        if (which == 0)      qb[((size_t)bh*NS + ss)*ND + dd] = bf;
        else if (which == 1) kb[((size_t)bh*NS + ss)*ND + dd] = bf;
        else                 vb[((size_t)bh*ND + dd)*NS + ss] = bf;
      }
    }
  }
}

// ---------------- flash attention (S^T form, reg-prefetched K/V) ----------------
__global__ __launch_bounds__(256, 4) void attn_kernel(
    const u16* __restrict__ qb, const u16* __restrict__ kb,
    const u16* __restrict__ vb, const int* __restrict__ lens,
    u16* __restrict__ ctx)
{
  __shared__ __align__(16) u16 smQ[2][64*32];
  __shared__ __align__(16) u16 smK[2][64*32];
  __shared__ __align__(16) u16 smV[2][64*32];
  __shared__ __align__(16) u16 smP[4][16*72];

  const int tid = threadIdx.x, lane = tid & 63, wave = tid >> 6;
  const int quad = lane >> 4, l16 = lane & 15;
  const int bh = blockIdx.y;
  const int b = bh / NH;
  const int h = bh - b*NH;
  const int q0 = blockIdx.x * 64;
  const int len = lens[b];

  // stage Q tile (64 rows x 64 d) async into LDS
  {
    int r = tid >> 2; int off = (tid & 3)*16;
    #pragma unroll
    for (int qc = 0; qc < 2; ++qc){
      const char* g = (const char*)qb + (size_t)(bh*NS + q0 + r)*128 + qc*64 + off;
      async16(g, (char*)smQ[qc] + wave*1024);
    }
  }

  // K/V register prefetch (tile 0)
  const int r0 = tid >> 2;
  const int ch = (tid & 3) * 16;
  const char* gk = (const char*)kb + ((size_t)bh*NS + r0)*128 + ch;
  const char* gv = (const char*)vb + ((size_t)(bh*ND + r0))*(NS*2) + ch;
  uint4 kp0 = *(const uint4*)(gk);
  uint4 kp1 = *(const uint4*)(gk + 64);
  uint4 vp0 = *(const uint4*)(gv);
  uint4 vp1 = *(const uint4*)(gv + 64);

  char* wK0 = (char*)smK[0] + r0*64 + ch;
  char* wK1 = (char*)smK[1] + r0*64 + ch;
  char* wV0 = (char*)smV[0] + r0*64 + ch;
  char* wV1 = (char*)smV[1] + r0*64 + ch;

  float m_i = -1e30f, l_i = 0.f;
  f32x4 accO[4] = {};
  const int ntiles = (len + 63) >> 6;

  for (int t = 0; t < ntiles; ++t){
    __syncthreads();                       // A: prior readers done; drains prefetch t
    *(uint4*)wK0 = kp0; *(uint4*)wK1 = kp1;
    *(uint4*)wV0 = vp0; *(uint4*)wV1 = vp1;
    __syncthreads();                       // C: writes visible; nothing outstanding
    if (t + 1 < ntiles){                   // D: issue prefetch t+1, drained at next A
      const char* nk = gk + (size_t)(t+1)*8192;
      const char* nv = gv + (size_t)(t+1)*128;
      kp0 = *(const uint4*)(nk); kp1 = *(const uint4*)(nk + 64);
      vp0 = *(const uint4*)(nv); vp1 = *(const uint4*)(nv + 64);
    }

    // S^T = K_tile . Q^T  (per wave: 64 keys x 16 q-rows)
    f32x4 accS[4] = {};
    #pragma unroll
    for (int kc = 0; kc < 2; ++kc){
      bf16x8 bq = *(const bf16x8*)&smQ[kc][(wave*16 + l16)*32 + quad*8];
      #pragma unroll
      for (int ni = 0; ni < 4; ++ni){
        bf16x8 ak = *(const bf16x8*)&smK[kc][(ni*16 + l16)*32 + quad*8];
        accS[ni] = __builtin_amdgcn_mfma_f32_16x16x32_bf16(ak, bq, accS[ni], 0, 0, 0);
      }
    }

    // online softmax: lane owns q-row (l16); keys = key0 + ni*16 + quad*4 + r
    int key0 = t*64;
    float mx = -3e38f;
    #pragma unroll
    for (int ni = 0; ni < 4; ++ni)
      #pragma unroll
      for (int r = 0; r < 4; ++r){
        int key = key0 + ni*16 + quad*4 + r;
        float x = (key < len) ? accS[ni][r] : -1e30f;
        accS[ni][r] = x;
        mx = fmaxf(mx, x);
      }
    mx = fmaxf(mx, __shfl_xor(mx, 16, 64));
    mx = fmaxf(mx, __shfl_xor(mx, 32, 64));
    float mnew = fmaxf(m_i, mx);
    float alpha = EXP2(m_i - mnew);
    float sum = 0.f;
    char* pRow = (char*)&smP[wave][0] + l16*144;
    #pragma unroll
    for (int ni = 0; ni < 4; ++ni){
      float p0 = EXP2(accS[ni][0] - mnew);
      float p1 = EXP2(accS[ni][1] - mnew);
      float p2 = EXP2(accS[ni][2] - mnew);
      float p3 = EXP2(accS[ni][3] - mnew);
      sum += (p0 + p1) + (p2 + p3);
      uint2 pr; pr.x = pack2bf(p0, p1); pr.y = pack2bf(p2, p3);
      *(uint2*)(pRow + ni*32 + quad*8) = pr;
    }
    sum += __shfl_xor(sum, 16, 64);
    sum += __shfl_xor(sum, 32, 64);
    l_i = l_i * alpha + sum;
    m_i = mnew;
    #pragma unroll
    for (int di = 0; di < 4; ++di) accO[di] *= alpha;
    asm volatile("s_waitcnt lgkmcnt(0)" ::: "memory");

    // O^T += V^T_tile . P^T
    #pragma unroll
    for (int kc = 0; kc < 2; ++kc){
      bf16x8 bp = *(const bf16x8*)(pRow + kc*64 + quad*16);
      #pragma unroll
      for (int di = 0; di < 4; ++di){
        bf16x8 av = *(const bf16x8*)&smV[kc][(di*16 + l16)*32 + quad*8];
        accO[di] = __builtin_amdgcn_mfma_f32_16x16x32_bf16(av, bp, accO[di], 0, 0, 0);
      }
    }
  }

  // epilogue: lane owns q-row; d = di*16 + quad*4 + r (4 consecutive -> b64 store)
  int q = q0 + wave*16 + l16;
  float inv = (q < len) ? (1.0f / l_i) : 0.f;
  size_t base = (size_t)(b*NS + q)*NE + h*ND;
  #pragma unroll
  for (int di = 0; di < 4; ++di){
    float v0 = accO[di][0]*inv, v1 = accO[di][1]*inv;
    float v2 = accO[di][2]*inv, v3 = accO[di][3]*inv;
    uint2 pr; pr.x = pack2bf(v0, v1); pr.y = pack2bf(v2, v3);
    *(uint2*)&ctx[base + di*16 + quad*4] = pr;
  }
}

// ---------------- output projection GEMM: [8192,768] x [768,768]^T -> fp32 ----------------
__global__ __launch_bounds__(256, 2) void gemm_out(
    const u16* __restrict__ A, const u16* __restrict__ Bw,
    const float* __restrict__ bias, float* __restrict__ out)
{
  __shared__ __align__(16) u16 smA[128*32];
  __shared__ __align__(16) u16 smB[128*32];
  const int tid = threadIdx.x;
  const int lane = tid & 63;
  const int wave = tid >> 6;
  const int wm = wave >> 1, wn = wave & 1;
  const int m0 = blockIdx.y * 128;
  const int n0 = blockIdx.x * 128;
  const int K = NE;

  f32x4 acc[4][4] = {};

  for (int kt = 0; kt < K; kt += 32){
    #pragma unroll
    for (int j = 0; j < 2; ++j){
      int c = j*256 + tid;
      int row = c >> 2;
      int off = (c & 3) * 16;
      const char* gA = (const char*)A + ((size_t)(m0+row)*K + kt)*2 + off;
      const char* gB = (const char*)Bw + ((size_t)(n0+row)*K + kt)*2 + off;
      char* lA = (char*)smA + (size_t)(j*256 + wave*64)*16;
      char* lB = (char*)smB + (size_t)(j*256 + wave*64)*16;
      async16(gA, lA);
      async16(gB, lB);
    }
    __syncthreads();
    int rA = wm*64 + (lane & 15);
    int rB = wn*64 + (lane & 15);
    int kk = (lane >> 4) * 8;
    bf16x8 av[4], bv[4];
    #pragma unroll
    for (int i = 0; i < 4; ++i){
      av[i] = *(const bf16x8*)&smA[(rA + i*16)*32 + kk];
      bv[i] = *(const bf16x8*)&smB[(rB + i*16)*32 + kk];
    }
    #pragma unroll
    for (int mi = 0; mi < 4; ++mi)
      #pragma unroll
      for (int ni = 0; ni < 4; ++ni)
        acc[mi][ni] = __builtin_amdgcn_mfma_f32_16x16x32_bf16(av[mi], bv[ni], acc[mi][ni], 0, 0, 0);
    __syncthreads();
  }

  int colbase = n0 + wn*64 + (lane & 15);
  #pragma unroll
  for (int ni = 0; ni < 4; ++ni){
    int gcol = colbase + ni*16;
    float bval = bias[gcol];
    #pragma unroll
    for (int mi = 0; mi < 4; ++mi){
      int rowb = m0 + wm*64 + mi*16 + (lane >> 4)*4;
      #pragma unroll
      for (int r = 0; r < 4; ++r){
        int grow = rowb + r;
        out[(size_t)grow*NE + gcol] = acc[mi][ni][r] + bval;
      }
    }
  }
}

extern "C" void kernel_launch(void* const* d_in, const int* in_sizes, int n_in,
                              void* d_out, int out_size, void* d_ws, size_t ws_size,
                              hipStream_t stream)
{
  const float* x    = (const float*)d_in[0];
  const void*  mask = d_in[1];
  const float* wqkv = (const float*)d_in[2];
  const float* bqkv = (const float*)d_in[3];
  const float* wout = (const float*)d_in[4];
  const float* bout = (const float*)d_in[5];

  char* ws = (char*)d_ws;
  u16* xb    = (u16*)(ws + 0);
  u16* wqkvb = (u16*)(ws + 12582912);
  u16* woutb = (u16*)(ws + 16121856);
  u16* qbuf  = (u16*)(ws + 17301504);
  u16* kbuf  = (u16*)(ws + 29884416);
  u16* vbuf  = (u16*)(ws + 42467328);
  u16* ctxb  = (u16*)(ws + 55050240);
  int* lens  = (int*)(ws + 67633152);

  cvt_kernel<<<6144, 256, 0, stream>>>(x,    xb,    6291456/4);
  cvt_kernel<<<1728, 256, 0, stream>>>(wqkv, wqkvb, 1769472/4);
  cvt_kernel<<<576,  256, 0, stream>>>(wout, woutb, 589824/4);
  lengths_kernel<<<1, 512, 0, stream>>>((const unsigned int*)mask, lens);
  gemm_qkv<<<dim3(18, 64), 256, 0, stream>>>(xb, wqkvb, bqkv, qbuf, kbuf, vbuf);
  attn_kernel<<<dim3(16, 96), 256, 0, stream>>>(qbuf, kbuf, vbuf, lens, ctxb);
  gemm_out<<<dim3(6, 64), 256, 0, stream>>>(ctxb, woutb, bout, (float*)d_out);
}